// Round 1
// baseline (111.715 us; speedup 1.0000x reference)
//
#include <hip/hip_runtime.h>
#include <cstdint>

// BasisFunction1D: out[o,b] = sum_i (1-d)*P[idx,o,i] + d*P[idx+1,o,i]
//   idx,d from Laplace-CDF bucketization of x[i,b] on a 128-chunk grid.
// Strategy:
//   K1 build_q: Q[i][g][o] = pack_f16x2( P[g,o,i], P[g+1,o,i]-P[g,o,i] )   (8.4 MB, u32)
//   K2 build_t: T[b][i]    = pack{ u16 idx, f16 d }                        (4.2 MB, u32)
//   K3 main:    wave owns one b, lanes span o (2 o/lane). Per i:
//               scalar load T -> idx (SALU), wvec={1.0h,d_h} (SALU),
//               coalesced dwordx2 gather of Q row, v_dot2_f32_f16 accumulate.
//               Epilogue LDS-transpose for coalesced-ish stores.

#define NG 128   // grids
#define NI 128   // input dim
#define NO 128   // output dim
#define NB 8192  // batch

using half2v = __attribute__((ext_vector_type(2))) _Float16;

__device__ inline uint32_t pack_f16x2(float lo, float hi) {
    _Float16 hl = (_Float16)lo, hh = (_Float16)hi;
    return (uint32_t)__builtin_bit_cast(unsigned short, hl) |
           ((uint32_t)__builtin_bit_cast(unsigned short, hh) << 16);
}

// ---- K1: transpose+delta-pack func_parameter -> Q[i][g][o] (f16x2) ----
__global__ __launch_bounds__(256) void build_q(const float* __restrict__ P,
                                               uint32_t* __restrict__ Q) {
    __shared__ float lp[32][129];
    __shared__ float ln[32][129];
    const int g  = blockIdx.x >> 2;
    const int o0 = (blockIdx.x & 3) * 32;
    const int t  = threadIdx.x;
    // load two g-slices, lanes vary i (coalesced)
    #pragma unroll
    for (int p = 0; p < 16; ++p) {
        int e = p * 256 + t;
        int ol = e >> 7, i = e & 127;
        lp[ol][i] = P[(size_t)(g * NO + o0 + ol) * NI + i];
        ln[ol][i] = P[(size_t)((g + 1) * NO + o0 + ol) * NI + i];
    }
    __syncthreads();
    // write Q, lanes vary o (coalesced); LDS read stride 129 -> conflict-free
    #pragma unroll
    for (int p = 0; p < 16; ++p) {
        int e = p * 256 + t;
        int i = e >> 5, ol = e & 31;
        float pl = lp[ol][i];
        float dd = ln[ol][i] - pl;
        Q[((size_t)i * NG + g) * NO + o0 + ol] = pack_f16x2(pl, dd);
    }
}

// ---- K2: bucketize x -> T[b][i] = {u16 idx | f16 d << 16} (transposed) ----
__global__ __launch_bounds__(256) void build_t(const float* __restrict__ x,
                                               const float* __restrict__ borders,
                                               const float* __restrict__ icl,
                                               uint32_t* __restrict__ T) {
    __shared__ uint32_t lt[32][33];
    const int bi = blockIdx.x & 3;   // i-tile (4 tiles of 32)
    const int bb = blockIdx.x >> 2;  // b-tile (256 tiles of 32)
    const int t  = threadIdx.x;
    #pragma unroll
    for (int p = 0; p < 4; ++p) {
        int e = p * 256 + t;
        int il = e >> 5, bl = e & 31;
        float xv = x[(size_t)(bi * 32 + il) * NB + bb * 32 + bl];
        float ea = __expf(-fabsf(xv));
        float cdf = xv > 0.f ? 1.f - 0.5f * ea : 0.5f * ea;
        int idx = (int)(cdf * 128.f);
        idx = idx > 127 ? 127 : idx;
        float d = (xv - borders[idx]) * icl[idx];
        _Float16 hd = (_Float16)d;
        lt[il][bl] = (uint32_t)idx |
                     ((uint32_t)__builtin_bit_cast(unsigned short, hd) << 16);
    }
    __syncthreads();
    #pragma unroll
    for (int p = 0; p < 4; ++p) {
        int e = p * 256 + t;
        int bl = e >> 5, il = e & 31;
        T[(size_t)(bb * 32 + bl) * NI + bi * 32 + il] = lt[il][bl];
    }
}

// ---- K3: main gather-dot kernel. 4 waves/block, 1 b per wave, 2 o per lane ----
__global__ __launch_bounds__(256) void main_k(const uint32_t* __restrict__ Q,
                                              const uint32_t* __restrict__ T,
                                              float* __restrict__ out) {
    __shared__ float sout[4][129];
    const int t    = threadIdx.x;
    const int wv   = t >> 6;
    const int lane = t & 63;
    const int b0   = blockIdx.x * 4;
    int b = __builtin_amdgcn_readfirstlane(b0 + wv);  // wave-uniform -> SMEM path
    const uint32_t* __restrict__ trow = T + (size_t)b * NI;
    const int o0 = lane * 2;
    float acc0 = 0.f, acc1 = 0.f;
    #pragma unroll 8
    for (int i = 0; i < NI; ++i) {
        uint32_t tw  = trow[i];                        // s_load (uniform)
        uint32_t idx = tw & 0xFFFFu;                   // SALU
        uint32_t wb  = (tw & 0xFFFF0000u) | 0x3C00u;   // {lo=1.0h, hi=d_h}
        const uint32_t* qrow = Q + ((size_t)((i << 7) + (int)idx) << 7);
        uint32_t q0 = qrow[o0];                        // coalesced dwordx2
        uint32_t q1 = qrow[o0 + 1];
        half2v w2 = __builtin_bit_cast(half2v, wb);
        acc0 = __builtin_amdgcn_fdot2(__builtin_bit_cast(half2v, q0), w2, acc0, false);
        acc1 = __builtin_amdgcn_fdot2(__builtin_bit_cast(half2v, q1), w2, acc1, false);
    }
    sout[wv][o0]     = acc0;
    sout[wv][o0 + 1] = acc1;
    __syncthreads();
    // store: lanes vary b-local fastest -> 16B runs, L2 merges lines
    #pragma unroll
    for (int p = 0; p < 2; ++p) {
        int e = p * 256 + t;
        int bl = e & 3, o = e >> 2;
        out[(size_t)o * NB + b0 + bl] = sout[bl][o];
    }
}

extern "C" void kernel_launch(void* const* d_in, const int* in_sizes, int n_in,
                              void* d_out, int out_size, void* d_ws, size_t ws_size,
                              hipStream_t stream) {
    const float* x       = (const float*)d_in[0];
    const float* P       = (const float*)d_in[1];
    const float* borders = (const float*)d_in[2];
    const float* icl     = (const float*)d_in[3];
    float* out = (float*)d_out;

    uint32_t* Q = (uint32_t*)d_ws;                       // 128*128*128 u32 = 8.4 MB
    uint32_t* T = Q + (size_t)NI * NG * NO;              // 8192*128  u32 = 4.2 MB

    hipLaunchKernelGGL(build_q, dim3(NG * 4), dim3(256), 0, stream, P, Q);
    hipLaunchKernelGGL(build_t, dim3((NB / 32) * 4), dim3(256), 0, stream,
                       x, borders, icl, T);
    hipLaunchKernelGGL(main_k, dim3(NB / 4), dim3(256), 0, stream, Q, T, out);
}